// Round 15
// baseline (346.227 us; speedup 1.0000x reference)
//
#include <hip/hip_runtime.h>
#include <hip/hip_bf16.h>

typedef unsigned short u16;
typedef unsigned int u32;
typedef float fx2 __attribute__((ext_vector_type(2)));

#define NXg 784
#define NYg 480
constexpr int N0c = NXg * NYg;   // 376320
constexpr int N1c = N0c / 4;     // 94080
constexpr int N2c = N0c / 16;    // 23520
constexpr int NTc = N0c + N1c + N2c;
constexpr int E0c = 4 * N0c;
constexpr int E1c = 4 * N1c;
constexpr int E2c = 4 * N2c;
// 512-node bins (kD granularity)
constexpr int NB0 = (N0c + 511) / 512;   // 735
constexpr int NB1 = (N1c + 511) / 512;   // 184
constexpr int NB2 = (N2c + 511) / 512;   // 46
constexpr int NBt = NB0 + NB1 + NB2;     // 965
constexpr int ECAP = 2560;               // BE capacity per bin (mean 2048, +11 sigma)
constexpr int CCAP = 4096;               // COL capacity per bin (= ECAP + 3*512)
// kC chunking (orthogonal to bins): 16384 edges per block
constexpr int CHUNK = 16384;
constexpr int NC0 = (E0c + CHUNK - 1) / CHUNK;   // 92
constexpr int NC1 = (E1c + CHUNK - 1) / CHUNK;   // 23
constexpr int NC2 = (E2c + CHUNK - 1) / CHUNK;   // 6
constexpr int NCt = NC0 + NC1 + NC2;             // 121

__device__ __forceinline__ float bf2f(u16 v) {
    union { u32 u; float f; } t; t.u = ((u32)v) << 16; return t.f;
}
__device__ __forceinline__ u16 f2bf(float f) {
    union { float f; u32 u; } t; t.f = f;
    u32 u = t.u;
    u32 r = (u + 0x7fffu + ((u >> 16) & 1u)) >> 16;   // RNE
    return (u16)r;
}
__device__ __forceinline__ float rdf(const void* p, int i, int isf32) {
    if (isf32) return ((const float*)p)[i];
    return bf2f(((const u16*)p)[i]);
}
__device__ __forceinline__ void stage(float* dst, const void* src, int n, int isf32) {
    int t = threadIdx.x;
    if (isf32) {
        const float* s = (const float*)src;
        for (int i = t; i < n; i += 256) dst[i] = s[i];
    } else {
        const u16* s = (const u16*)src;
        for (int i = t; i < n; i += 256) dst[i] = bf2f(s[i]);
    }
}

struct BF16S {
    typedef u16 T;
    static __device__ __forceinline__ float ld(const T* p, size_t i) { return bf2f(p[i]); }
    static __device__ __forceinline__ void st(T* p, size_t i, float v) { p[i] = f2bf(v); }
    static __device__ __forceinline__ fx2 ld2(const T* p, size_t i) {
        u32 w = ((const u32*)p)[i];
        fx2 r; r.x = bf2f((u16)(w & 0xffffu)); r.y = bf2f((u16)(w >> 16));
        return r;
    }
    static __device__ __forceinline__ void st2nt(T* p, size_t i, fx2 v) {
        u32 w = (u32)f2bf(v.x) | ((u32)f2bf(v.y) << 16);
        __builtin_nontemporal_store(w, (u32*)p + i);
    }
};

__device__ __forceinline__ void lvl_of_bin(int b, int& lv, int& bl) {
    if (b < NB0) { lv = 0; bl = b; }
    else if (b < NB0 + NB1) { lv = 1; bl = b - NB0; }
    else { lv = 2; bl = b - NB0 - NB1; }
}

// ------------- detect dtype + init cursors + dummy ys rows -------------
__global__ void k_dinit(const u32* __restrict__ xw, int* __restrict__ flag,
                        int* __restrict__ binCursor, u16* __restrict__ y0,
                        u16* __restrict__ y1, u16* __restrict__ y2) {
    __shared__ int cnt;
    int t = threadIdx.x;
    int g = blockIdx.x * 256 + t;
    if (blockIdx.x == 0) {
        if (t == 0) cnt = 0;
        __syncthreads();
        u32 w = xw[t];
        int e = (int)((w >> 7) & 0xFFu);
        int hit = ((e >= 90 && e <= 135) || ((w & 0x7FFFu) == 0u)) ? 1 : 0;
        atomicAdd(&cnt, hit);
        __syncthreads();
        if (t == 0) *flag = (cnt < 192) ? 1 : 0;
    }
    if (g < NBt) binCursor[g] = g * ECAP;     // fixed-capacity BE bases
    if (blockIdx.x == 1 && t < 32) { y0[t] = 0; y1[t] = 0; y2[t] = 0; }
}

// ------------- phase C: hist + reserve + place packed (src<<9 | dstLow) -------------
// 16384-edge chunks per block (orthogonal to 512-node bins)
__global__ void kC_place(const int* __restrict__ ei0, const int* __restrict__ ei1,
                         const int* __restrict__ ei2, int* __restrict__ binCursor,
                         u32* __restrict__ BE) {
    __shared__ int lc[NB0];
    __shared__ int lb[NB0];
    int b = blockIdx.x, t = threadIdx.x;
    int lv, cl;
    if (b < NC0) { lv = 0; cl = b; }
    else if (b < NC0 + NC1) { lv = 1; cl = b - NC0; }
    else { lv = 2; cl = b - NC0 - NC1; }
    const int* srcp; const int* dstp; int E, nb, binB;
    if (lv == 0) { srcp = ei0; dstp = ei0 + E0c; E = E0c; nb = NB0; binB = 0; }
    else if (lv == 1) { srcp = ei1; dstp = ei1 + E1c; E = E1c; nb = NB1; binB = NB0; }
    else { srcp = ei2; dstp = ei2 + E2c; E = E2c; nb = NB2; binB = NB0 + NB1; }
    for (int i = t; i < nb; i += 256) lc[i] = 0;
    __syncthreads();
    int e0 = cl * CHUNK, e1 = min(E, e0 + CHUNK);
    for (int i = e0 + t; i < e1; i += 256) atomicAdd(&lc[dstp[i] >> 9], 1);
    __syncthreads();
    for (int i = t; i < nb; i += 256) {
        int c = lc[i];
        lb[i] = c ? atomicAdd(&binCursor[binB + i], c) : 0;
        lc[i] = 0;
    }
    __syncthreads();
    for (int i = e0 + t; i < e1; i += 256) {
        int d = dstp[i];
        int bn = d >> 9;
        int p = atomicAdd(&lc[bn], 1);
        BE[lb[bn] + p] = ((u32)srcp[i] << 9) | (u32)(d & 511);
    }
}

// ------------- phase D: counts -> DINV + RPC + COL fill/scatter (fixed regions) -------------
__global__ void kD_all(const u32* __restrict__ BE, const int* __restrict__ binCursor,
                       float* __restrict__ DINV, u32* __restrict__ RPC,
                       int* __restrict__ colAll) {
    __shared__ int lc[512];
    __shared__ int lst[512];
    __shared__ int lcur[512];
    __shared__ int red[256];
    int b = blockIdx.x, t = threadIdx.x;
    int lv, bl; lvl_of_bin(b, lv, bl);
    int cbase, nLev, dummy;
    if (lv == 0) { cbase = 0; nLev = N0c; dummy = N0c; }
    else if (lv == 1) { cbase = N0c; nLev = N1c; dummy = N1c; }
    else { cbase = N0c + N1c; nLev = N2c; dummy = N2c; }
    lc[t] = 0; lc[t + 256] = 0;
    __syncthreads();
    int s0 = b * ECAP, s1 = binCursor[b];
    for (int i = s0 + t; i < s1; i += 256) atomicAdd(&lc[BE[i] & 511u], 1);
    __syncthreads();
    int nodeB = bl << 9;
    int pc[2];
    int ps = 0;
#pragma unroll
    for (int j = 0; j < 2; j++) {
        int li = t * 2 + j;
        int node = nodeB + li;
        int c = (node < nLev) ? lc[li] : 0;
        pc[j] = (c + 3) & ~3;
        ps += pc[j];
    }
    red[t] = ps;
    __syncthreads();
    for (int off = 1; off < 256; off <<= 1) {
        int x = (t >= off) ? red[t - off] : 0;
        __syncthreads();
        red[t] += x;
        __syncthreads();
    }
    int ex = red[t] - ps;
    int tot = red[255];
    int cb = b * CCAP;
    int off = ex;
#pragma unroll
    for (int j = 0; j < 2; j++) {
        int li = t * 2 + j;
        lst[li] = off;
        lcur[li] = off;
        off += pc[j];
    }
    __syncthreads();
#pragma unroll
    for (int j = 0; j < 2; j++) {
        int li = t * 2 + j;
        int node = nodeB + li;
        if (node < nLev) {
            int c = lc[li];
            DINV[cbase + node] = rsqrtf((float)c + 1.0f);
            int rp = cb + lst[li];                    // multiple of 4
            u32 nch = (u32)((c + 3) >> 2);
            RPC[cbase + node] = ((u32)(rp >> 2) << 10) | nch;
        }
    }
    for (int i = t; i < tot; i += 256) colAll[cb + i] = dummy;
    __syncthreads();
    for (int i = s0 + t; i < s1; i += 256) {
        u32 e = BE[i];
        int p = atomicAdd(&lcur[e & 511u], 1);
        colAll[cb + p] = (int)(e >> 9);
    }
}

// ---------------- 2-wide gather core (RPC: packed rowptr|nch) ----------------
__device__ __forceinline__ fx2 gather2(const u16* __restrict__ ys,
                                       const u32* __restrict__ rpc,
                                       const int* __restrict__ col,
                                       const float* __restrict__ dinv,
                                       int node, int cp) {
    u32 v = rpc[node];
    int s0 = (int)((v >> 10) << 2);
    int nch = (int)(v & 1023u);
    fx2 a = BF16S::ld2(ys, (size_t)node * 16 + cp);
    const int4* c4 = (const int4*)(col + s0);
    for (int i = 0; i < nch; i++) {
        int4 cs = c4[i];
        fx2 a0 = BF16S::ld2(ys, (size_t)cs.x * 16 + cp);
        fx2 a1 = BF16S::ld2(ys, (size_t)cs.y * 16 + cp);
        fx2 a2 = BF16S::ld2(ys, (size_t)cs.z * 16 + cp);
        fx2 a3 = BF16S::ld2(ys, (size_t)cs.w * 16 + cp);
        a += (a0 + a1) + (a2 + a3);
    }
    float di = dinv[node];
    a *= di;
    return a;
}

// ---------------- K1: persistent fc1 + relu + prep1 -> bf16 ys (tiled) ----------------
constexpr int FC1_TILES = N0c / 64;   // 5880
__global__ void k_fc1prep(const void* __restrict__ x, const void* __restrict__ fw,
                          const void* __restrict__ fb, const void* __restrict__ w1,
                          const float* __restrict__ d0, u16* __restrict__ ys1,
                          const int* __restrict__ flag) {
    int isf32 = *flag;
    __shared__ float sx[256];
    __shared__ float sh[64 * 33];
    __shared__ float sfw[128];
    __shared__ float sfb[32];
    __shared__ float sw1[1024];
    int t = threadIdx.x;
    stage(sw1, w1, 1024, isf32);
    stage(sfw, fw, 128, isf32);
    stage(sfb, fb, 32, isf32);
    __syncthreads();
    int c = t & 31;
    int ng = t >> 5;       // 0..7
    int ci0 = t & 15;
    int rgrp = t >> 4;     // 0..15
    for (int tile = blockIdx.x; tile < FC1_TILES; tile += gridDim.x) {
        int nodeBase = tile * 64;
        sx[t] = rdf(x, nodeBase * 4 + t, isf32);
        __syncthreads();
#pragma unroll
        for (int i = 0; i < 8; i++) {
            int ln = ng + i * 8;
            float a = sfb[c];
#pragma unroll
            for (int k = 0; k < 4; k++) a = fmaf(sx[ln * 4 + k], sfw[k * 32 + c], a);
            sh[ln * 33 + c] = fmaxf(a, 0.0f);
        }
        __syncthreads();
        float acc[4][2];
#pragma unroll
        for (int r = 0; r < 4; r++) { acc[r][0] = 0.0f; acc[r][1] = 0.0f; }
#pragma unroll
        for (int k = 0; k < 32; k++) {
            float w0 = sw1[k * 32 + ci0];
            float w1v = sw1[k * 32 + ci0 + 16];
#pragma unroll
            for (int r = 0; r < 4; r++) {
                float s = sh[(rgrp * 4 + r) * 33 + k];
                acc[r][0] = fmaf(s, w0, acc[r][0]);
                acc[r][1] = fmaf(s, w1v, acc[r][1]);
            }
        }
#pragma unroll
        for (int r = 0; r < 4; r++) {
            int node = nodeBase + rgrp * 4 + r;
            float dv = d0[node];
            BF16S::st(ys1, (size_t)node * 32 + ci0, acc[r][0] * dv);
            BF16S::st(ys1, (size_t)node * 32 + ci0 + 16, acc[r][1] * dv);
        }
        __syncthreads();
    }
}

// ---------------- K2/K3: NPB nodes/block, gather + relu -> O; fused prep_next ----------------
template <int NPB>
__global__ void k_gds(const u16* __restrict__ ys_in, const u32* __restrict__ rpc,
                      const int* __restrict__ col,
                      const float* __restrict__ dinv_p, const void* __restrict__ b,
                      u16* __restrict__ O, const void* __restrict__ wn,
                      const float* __restrict__ dinv_c, u16* __restrict__ ys_out,
                      int cols, const int* __restrict__ flag) {
    int isf32 = *flag;
    __shared__ float sv[NPB * 32];
    __shared__ float swn[1024];
    int t = threadIdx.x;
    int nodeBase = blockIdx.x * NPB;
    int rb = nodeBase / cols;                    // cols % NPB == 0 -> whole block same row
    if (!(rb & 1)) stage(swn, wn, 1024, isf32);  // block-uniform
    int cp = t & 15;
#pragma unroll
    for (int i = 0; i < NPB / 16; i++) {
        int local = (t >> 4) + i * 16;
        int node = nodeBase + local;
        fx2 g = gather2(ys_in, rpc, col, dinv_p, node, cp);
        fx2 v;
        v.x = fmaxf(g.x + rdf(b, 2 * cp, isf32), 0.0f);
        v.y = fmaxf(g.y + rdf(b, 2 * cp + 1, isf32), 0.0f);
        BF16S::st2nt(O, (size_t)node * 16 + cp, v);
        sv[local * 32 + 2 * cp] = v.x;
        sv[local * 32 + 2 * cp + 1] = v.y;
    }
    __syncthreads();
    if (!(rb & 1)) {
#pragma unroll
        for (int i = 0; i < NPB / 16; i++) {
            int item = t + i * 256;
            int childIdx = item >> 5;        // 0..NPB/2-1
            int ci = item & 31;
            int lc = childIdx * 2;           // even local node
            int cc = (nodeBase - rb * cols) + lc;
            int dn = (rb >> 1) * (cols >> 1) + (cc >> 1);
            float a = 0.0f;
#pragma unroll
            for (int k = 0; k < 32; k++) a = fmaf(sv[lc * 32 + k], swn[k * 32 + ci], a);
            BF16S::st(ys_out, (size_t)dn * 32 + ci, a * dinv_c[dn]);
        }
    }
}

// ---------------- K4/K5: NPB parents/block, gather + up-residual + tiled prep_next ----------------
template <int NPB>
__global__ void k_gup(const u16* __restrict__ ys_in, const u32* __restrict__ rpc,
                      const int* __restrict__ col,
                      const float* __restrict__ dinv_p, const void* __restrict__ b,
                      const u16* __restrict__ R, const void* __restrict__ wn,
                      const float* __restrict__ dinv_c, u16* __restrict__ ys_out,
                      int cols_p, const int* __restrict__ flag) {
    constexpr int RPT = NPB / 4;            // child rows per thread
    int isf32 = *flag;
    __shared__ float sv[NPB * 32];
    __shared__ float sch[NPB * 4 * 33];     // padded child rows
    __shared__ float swn[1024];
    int t = threadIdx.x;
    int nodeBase = blockIdx.x * NPB;
    stage(swn, wn, 1024, isf32);
    if (t < NPB * 16) {
        int local = t >> 4, cp = t & 15;
        int node = nodeBase + local;
        fx2 g = gather2(ys_in, rpc, col, dinv_p, node, cp);
        sv[local * 32 + 2 * cp] = fmaxf(g.x + rdf(b, 2 * cp, isf32), 0.0f);
        sv[local * 32 + 2 * cp + 1] = fmaxf(g.y + rdf(b, 2 * cp + 1, isf32), 0.0f);
    }
    __syncthreads();
    int rb = nodeBase / cols_p;
    int ccb = nodeBase - rb * cols_p;
    int cols_c = cols_p * 2;
#pragma unroll
    for (int i = 0; i < NPB / 2; i++) {
        int item = t + i * 256;
        int row = item >> 5, k = item & 31;
        int lp = row >> 2, j = row & 3;
        int ch = (2 * rb + (j >> 1)) * cols_c + 2 * (ccb + lp) + (j & 1);
        sch[row * 33 + k] = bf2f(R[(size_t)ch * 32 + k]) + sv[lp * 32 + k];
    }
    __syncthreads();
    int ci0 = t & 15;
    int rgrp = t >> 4;   // 0..15
    float acc[RPT][2];
#pragma unroll
    for (int r = 0; r < RPT; r++) { acc[r][0] = 0.0f; acc[r][1] = 0.0f; }
#pragma unroll
    for (int k = 0; k < 32; k++) {
        float w0 = swn[k * 32 + ci0];
        float w1v = swn[k * 32 + ci0 + 16];
#pragma unroll
        for (int r = 0; r < RPT; r++) {
            float s = sch[(rgrp * RPT + r) * 33 + k];
            acc[r][0] = fmaf(s, w0, acc[r][0]);
            acc[r][1] = fmaf(s, w1v, acc[r][1]);
        }
    }
#pragma unroll
    for (int r = 0; r < RPT; r++) {
        int row = rgrp * RPT + r;
        int lp = row >> 2, j = row & 3;
        int ch = (2 * rb + (j >> 1)) * cols_c + 2 * (ccb + lp) + (j & 1);
        float dc = dinv_c[ch];
        BF16S::st(ys_out, (size_t)ch * 32 + ci0, acc[r][0] * dc);
        BF16S::st(ys_out, (size_t)ch * 32 + ci0 + 16, acc[r][1] * dc);
    }
}

// ---------------- K6: 32 nodes/block, gather + relu + fc2 -> out ----------------
__global__ void k_gfc2(const u16* __restrict__ ys, const u32* __restrict__ rpc,
                       const int* __restrict__ col,
                       const float* __restrict__ dinv, const void* __restrict__ b5,
                       const void* __restrict__ fw, const void* __restrict__ fb,
                       void* __restrict__ out, int n, const int* __restrict__ flag) {
    int isf32 = *flag;
    __shared__ float sv[1024];
    __shared__ float sw[96];
    __shared__ float sfb[3];
    int t = threadIdx.x;
    if (t < 96) sw[t] = rdf(fw, t, isf32);
    if (t < 3) sfb[t] = rdf(fb, t, isf32);
    int nodeBase = blockIdx.x * 32;
    int cp = t & 15;
#pragma unroll
    for (int i = 0; i < 2; i++) {
        int local = (t >> 4) + i * 16;
        int node = nodeBase + local;
        fx2 g = gather2(ys, rpc, col, dinv, node, cp);
        sv[local * 32 + 2 * cp] = fmaxf(g.x + rdf(b5, 2 * cp, isf32), 0.0f);
        sv[local * 32 + 2 * cp + 1] = fmaxf(g.y + rdf(b5, 2 * cp + 1, isf32), 0.0f);
    }
    __syncthreads();
    if (t < 96) {
        int ln = t / 3, j = t - ln * 3;
        int gn = nodeBase + ln;
        float o = sfb[j];
#pragma unroll
        for (int k = 0; k < 32; k++) o = fmaf(sv[ln * 32 + k], sw[k * 3 + j], o);
        if (isf32) ((float*)out)[(size_t)gn * 3 + j] = o;
        else ((u16*)out)[(size_t)gn * 3 + j] = f2bf(o);
    }
}

extern "C" void kernel_launch(void* const* d_in, const int* in_sizes, int n_in,
                              void* d_out, int out_size, void* d_ws, size_t ws_size,
                              hipStream_t stream) {
    const void* x    = d_in[0];
    const void* fc1w = d_in[1];
    const void* fc1b = d_in[2];
    const void* w1 = d_in[3];  const void* b1 = d_in[4];
    const void* w2 = d_in[5];  const void* b2 = d_in[6];
    const void* w3 = d_in[7];  const void* b3 = d_in[8];
    const void* w4 = d_in[9];  const void* b4 = d_in[10];
    const void* w5 = d_in[11]; const void* b5 = d_in[12];
    const void* fc2w = d_in[13]; const void* fc2b = d_in[14];
    const int* ei0 = (const int*)d_in[18];
    const int* ei1 = (const int*)d_in[19];
    const int* ei2 = (const int*)d_in[20];

    u16* YS0 = (u16*)d_ws;                                  // (N0+1)*32
    u16* A   = YS0 + (size_t)(N0c + 1) * 32;                // N0*32  (h_b residual)
    u16* YS1 = A + (size_t)N0c * 32;                        // (N1+1)*32
    u16* H1  = YS1 + (size_t)(N1c + 1) * 32;                // N1*32  (h1_b residual)
    u16* YS2 = H1 + (size_t)N1c * 32;                       // (N2+1)*32
    float* DINV = (float*)(YS2 + (size_t)(N2c + 1) * 32);   // NT
    u32* RPC  = (u32*)(DINV + NTc);                         // NT
    int* COLA = (int*)(RPC + NTc);                          // NBt*CCAP
    u32* BE   = (u32*)(COLA + (size_t)NBt * CCAP);          // NBt*ECAP
    int* binCursor = (int*)(BE + (size_t)NBt * ECAP);       // NBt
    int* FLAG      = binCursor + NBt;

    float* D0 = DINV; float* D1 = D0 + N0c; float* D2 = D1 + N1c;
    u32* RPC0 = RPC; u32* RPC1 = RPC0 + N0c; u32* RPC2 = RPC1 + N1c;

    const int Bk = 256;

    k_dinit<<<4, Bk, 0, stream>>>((const u32*)x, FLAG, binCursor,
                                  YS0 + (size_t)N0c * 32, YS1 + (size_t)N1c * 32,
                                  YS2 + (size_t)N2c * 32);
    kC_place<<<NCt, Bk, 0, stream>>>(ei0, ei1, ei2, binCursor, BE);
    kD_all<<<NBt, Bk, 0, stream>>>(BE, binCursor, DINV, RPC, COLA);

    // K1: persistent fc1+relu+prep1 -> YS0
    k_fc1prep<<<1960, Bk, 0, stream>>>(x, fc1w, fc1b, w1, D0, YS0, FLAG);
    // K2: gather1 -> A, fused prep2 -> YS1
    k_gds<32><<<N0c / 32, Bk, 0, stream>>>(YS0, RPC0, COLA, D0, b1, A, w2, D1, YS1, NYg, FLAG);
    // K3: gather2 -> H1, fused prep3 -> YS2
    k_gds<16><<<N1c / 16, Bk, 0, stream>>>(YS1, RPC1, COLA, D1, b2, H1, w3, D2, YS2, NYg / 2, FLAG);
    // K4: gather3 + up-residual(H1) + prep4 -> YS1; 8 parents
    k_gup<8><<<N2c / 8, Bk, 0, stream>>>(YS2, RPC2, COLA, D2, b3, H1, w4, D1, YS1, NYg / 4, FLAG);
    // K5: gather4 + up-residual(A) + prep5 -> YS0; 16 parents
    k_gup<16><<<N1c / 16, Bk, 0, stream>>>(YS1, RPC1, COLA, D1, b4, A, w5, D0, YS0, NYg / 2, FLAG);
    // K6: gather5 + fc2 -> out
    k_gfc2<<<N0c / 32, Bk, 0, stream>>>(YS0, RPC0, COLA, D0, b5, fc2w, fc2b, d_out, N0c, FLAG);
}

// Round 16
// 311.504 us; speedup vs baseline: 1.1115x; 1.1115x over previous
//
#include <hip/hip_runtime.h>
#include <hip/hip_bf16.h>

typedef unsigned short u16;
typedef unsigned int u32;
typedef float fx2 __attribute__((ext_vector_type(2)));

#define NXg 784
#define NYg 480
constexpr int N0c = NXg * NYg;   // 376320
constexpr int N1c = N0c / 4;     // 94080
constexpr int N2c = N0c / 16;    // 23520
constexpr int NTc = N0c + N1c + N2c;
constexpr int E0c = 4 * N0c;
constexpr int E1c = 4 * N1c;
constexpr int E2c = 4 * N2c;
// 512-node bins (kD granularity)
constexpr int NB0 = (N0c + 511) / 512;   // 735
constexpr int NB1 = (N1c + 511) / 512;   // 184
constexpr int NB2 = (N2c + 511) / 512;   // 46
constexpr int NBt = NB0 + NB1 + NB2;     // 965
constexpr int ECAP = 2560;               // BE capacity per bin (mean 2048, +11 sigma)
constexpr int CCAP = 4096;               // COL capacity per bin (= ECAP + 3*512)
// kC chunking: 8192 edges per 1024-thread block
constexpr int CHUNK = 8192;
constexpr int NC0 = (E0c + CHUNK - 1) / CHUNK;   // 184
constexpr int NC1 = (E1c + CHUNK - 1) / CHUNK;   // 46
constexpr int NC2 = (E2c + CHUNK - 1) / CHUNK;   // 12
constexpr int NCt = NC0 + NC1 + NC2;             // 242

__device__ __forceinline__ float bf2f(u16 v) {
    union { u32 u; float f; } t; t.u = ((u32)v) << 16; return t.f;
}
__device__ __forceinline__ u16 f2bf(float f) {
    union { float f; u32 u; } t; t.f = f;
    u32 u = t.u;
    u32 r = (u + 0x7fffu + ((u >> 16) & 1u)) >> 16;   // RNE
    return (u16)r;
}
__device__ __forceinline__ float rdf(const void* p, int i, int isf32) {
    if (isf32) return ((const float*)p)[i];
    return bf2f(((const u16*)p)[i]);
}
__device__ __forceinline__ void stage(float* dst, const void* src, int n, int isf32) {
    int t = threadIdx.x;
    if (isf32) {
        const float* s = (const float*)src;
        for (int i = t; i < n; i += 256) dst[i] = s[i];
    } else {
        const u16* s = (const u16*)src;
        for (int i = t; i < n; i += 256) dst[i] = bf2f(s[i]);
    }
}

struct BF16S {
    typedef u16 T;
    static __device__ __forceinline__ float ld(const T* p, size_t i) { return bf2f(p[i]); }
    static __device__ __forceinline__ void st(T* p, size_t i, float v) { p[i] = f2bf(v); }
    static __device__ __forceinline__ fx2 ld2(const T* p, size_t i) {
        u32 w = ((const u32*)p)[i];
        fx2 r; r.x = bf2f((u16)(w & 0xffffu)); r.y = bf2f((u16)(w >> 16));
        return r;
    }
    static __device__ __forceinline__ void st2nt(T* p, size_t i, fx2 v) {
        u32 w = (u32)f2bf(v.x) | ((u32)f2bf(v.y) << 16);
        __builtin_nontemporal_store(w, (u32*)p + i);
    }
};

__device__ __forceinline__ void lvl_of_bin(int b, int& lv, int& bl) {
    if (b < NB0) { lv = 0; bl = b; }
    else if (b < NB0 + NB1) { lv = 1; bl = b - NB0; }
    else { lv = 2; bl = b - NB0 - NB1; }
}

// ------------- detect dtype + init cursors + dummy ys rows -------------
__global__ void k_dinit(const u32* __restrict__ xw, int* __restrict__ flag,
                        int* __restrict__ binCursor, u16* __restrict__ y0,
                        u16* __restrict__ y1, u16* __restrict__ y2) {
    __shared__ int cnt;
    int t = threadIdx.x;
    int g = blockIdx.x * 256 + t;
    if (blockIdx.x == 0) {
        if (t == 0) cnt = 0;
        __syncthreads();
        u32 w = xw[t];
        int e = (int)((w >> 7) & 0xFFu);
        int hit = ((e >= 90 && e <= 135) || ((w & 0x7FFFu) == 0u)) ? 1 : 0;
        atomicAdd(&cnt, hit);
        __syncthreads();
        if (t == 0) *flag = (cnt < 192) ? 1 : 0;
    }
    if (g < NBt) binCursor[g] = g * ECAP;     // fixed-capacity BE bases
    if (blockIdx.x == 1 && t < 32) { y0[t] = 0; y1[t] = 0; y2[t] = 0; }
}

// ------------- phase C: hist + reserve + place packed (src<<9 | dstLow) -------------
// 8192-edge chunks per 1024-thread block
__global__ void kC_place(const int* __restrict__ ei0, const int* __restrict__ ei1,
                         const int* __restrict__ ei2, int* __restrict__ binCursor,
                         u32* __restrict__ BE) {
    __shared__ int lc[NB0];
    __shared__ int lb[NB0];
    int b = blockIdx.x, t = threadIdx.x;
    int lv, cl;
    if (b < NC0) { lv = 0; cl = b; }
    else if (b < NC0 + NC1) { lv = 1; cl = b - NC0; }
    else { lv = 2; cl = b - NC0 - NC1; }
    const int* srcp; const int* dstp; int E, nb, binB;
    if (lv == 0) { srcp = ei0; dstp = ei0 + E0c; E = E0c; nb = NB0; binB = 0; }
    else if (lv == 1) { srcp = ei1; dstp = ei1 + E1c; E = E1c; nb = NB1; binB = NB0; }
    else { srcp = ei2; dstp = ei2 + E2c; E = E2c; nb = NB2; binB = NB0 + NB1; }
    for (int i = t; i < nb; i += 1024) lc[i] = 0;
    __syncthreads();
    int e0 = cl * CHUNK, e1 = min(E, e0 + CHUNK);
    for (int i = e0 + t; i < e1; i += 1024) atomicAdd(&lc[dstp[i] >> 9], 1);
    __syncthreads();
    for (int i = t; i < nb; i += 1024) {
        int c = lc[i];
        lb[i] = c ? atomicAdd(&binCursor[binB + i], c) : 0;
        lc[i] = 0;
    }
    __syncthreads();
    for (int i = e0 + t; i < e1; i += 1024) {
        int d = dstp[i];
        int bn = d >> 9;
        int p = atomicAdd(&lc[bn], 1);
        BE[lb[bn] + p] = ((u32)srcp[i] << 9) | (u32)(d & 511);
    }
}

// ------------- phase D: counts -> DINV + RPC + COL fill/scatter (fixed regions) -------------
__global__ void kD_all(const u32* __restrict__ BE, const int* __restrict__ binCursor,
                       float* __restrict__ DINV, u32* __restrict__ RPC,
                       int* __restrict__ colAll) {
    __shared__ int lc[512];
    __shared__ int lst[512];
    __shared__ int lcur[512];
    __shared__ int red[256];
    int b = blockIdx.x, t = threadIdx.x;
    int lv, bl; lvl_of_bin(b, lv, bl);
    int cbase, nLev, dummy;
    if (lv == 0) { cbase = 0; nLev = N0c; dummy = N0c; }
    else if (lv == 1) { cbase = N0c; nLev = N1c; dummy = N1c; }
    else { cbase = N0c + N1c; nLev = N2c; dummy = N2c; }
    lc[t] = 0; lc[t + 256] = 0;
    __syncthreads();
    int s0 = b * ECAP, s1 = binCursor[b];
    for (int i = s0 + t; i < s1; i += 256) atomicAdd(&lc[BE[i] & 511u], 1);
    __syncthreads();
    int nodeB = bl << 9;
    int pc[2];
    int ps = 0;
#pragma unroll
    for (int j = 0; j < 2; j++) {
        int li = t * 2 + j;
        int node = nodeB + li;
        int c = (node < nLev) ? lc[li] : 0;
        pc[j] = (c + 3) & ~3;
        ps += pc[j];
    }
    red[t] = ps;
    __syncthreads();
    for (int off = 1; off < 256; off <<= 1) {
        int x = (t >= off) ? red[t - off] : 0;
        __syncthreads();
        red[t] += x;
        __syncthreads();
    }
    int ex = red[t] - ps;
    int tot = red[255];
    int cb = b * CCAP;
    int off = ex;
#pragma unroll
    for (int j = 0; j < 2; j++) {
        int li = t * 2 + j;
        lst[li] = off;
        lcur[li] = off;
        off += pc[j];
    }
    __syncthreads();
#pragma unroll
    for (int j = 0; j < 2; j++) {
        int li = t * 2 + j;
        int node = nodeB + li;
        if (node < nLev) {
            int c = lc[li];
            DINV[cbase + node] = rsqrtf((float)c + 1.0f);
            int rp = cb + lst[li];                    // multiple of 4
            u32 nch = (u32)((c + 3) >> 2);
            RPC[cbase + node] = ((u32)(rp >> 2) << 10) | nch;
        }
    }
    for (int i = t; i < tot; i += 256) colAll[cb + i] = dummy;
    __syncthreads();
    for (int i = s0 + t; i < s1; i += 256) {
        u32 e = BE[i];
        int p = atomicAdd(&lcur[e & 511u], 1);
        colAll[cb + p] = (int)(e >> 9);
    }
}

// ---------------- 2-wide gather core (RPC: packed rowptr|nch) ----------------
__device__ __forceinline__ fx2 gather2(const u16* __restrict__ ys,
                                       const u32* __restrict__ rpc,
                                       const int* __restrict__ col,
                                       const float* __restrict__ dinv,
                                       int node, int cp) {
    u32 v = rpc[node];
    int s0 = (int)((v >> 10) << 2);
    int nch = (int)(v & 1023u);
    fx2 a = BF16S::ld2(ys, (size_t)node * 16 + cp);
    const int4* c4 = (const int4*)(col + s0);
    for (int i = 0; i < nch; i++) {
        int4 cs = c4[i];
        fx2 a0 = BF16S::ld2(ys, (size_t)cs.x * 16 + cp);
        fx2 a1 = BF16S::ld2(ys, (size_t)cs.y * 16 + cp);
        fx2 a2 = BF16S::ld2(ys, (size_t)cs.z * 16 + cp);
        fx2 a3 = BF16S::ld2(ys, (size_t)cs.w * 16 + cp);
        a += (a0 + a1) + (a2 + a3);
    }
    float di = dinv[node];
    a *= di;
    return a;
}

// ---------------- K1: persistent fc1 + relu + prep1 -> bf16 ys (tiled) ----------------
constexpr int FC1_TILES = N0c / 64;   // 5880
__global__ void k_fc1prep(const void* __restrict__ x, const void* __restrict__ fw,
                          const void* __restrict__ fb, const void* __restrict__ w1,
                          const float* __restrict__ d0, u16* __restrict__ ys1,
                          const int* __restrict__ flag) {
    int isf32 = *flag;
    __shared__ float sx[256];
    __shared__ float sh[64 * 33];
    __shared__ float sfw[128];
    __shared__ float sfb[32];
    __shared__ float sw1[1024];
    int t = threadIdx.x;
    stage(sw1, w1, 1024, isf32);
    stage(sfw, fw, 128, isf32);
    stage(sfb, fb, 32, isf32);
    __syncthreads();
    int c = t & 31;
    int ng = t >> 5;       // 0..7
    int ci0 = t & 15;
    int rgrp = t >> 4;     // 0..15
    for (int tile = blockIdx.x; tile < FC1_TILES; tile += gridDim.x) {
        int nodeBase = tile * 64;
        sx[t] = rdf(x, nodeBase * 4 + t, isf32);
        __syncthreads();
#pragma unroll
        for (int i = 0; i < 8; i++) {
            int ln = ng + i * 8;
            float a = sfb[c];
#pragma unroll
            for (int k = 0; k < 4; k++) a = fmaf(sx[ln * 4 + k], sfw[k * 32 + c], a);
            sh[ln * 33 + c] = fmaxf(a, 0.0f);
        }
        __syncthreads();
        float acc[4][2];
#pragma unroll
        for (int r = 0; r < 4; r++) { acc[r][0] = 0.0f; acc[r][1] = 0.0f; }
#pragma unroll
        for (int k = 0; k < 32; k++) {
            float w0 = sw1[k * 32 + ci0];
            float w1v = sw1[k * 32 + ci0 + 16];
#pragma unroll
            for (int r = 0; r < 4; r++) {
                float s = sh[(rgrp * 4 + r) * 33 + k];
                acc[r][0] = fmaf(s, w0, acc[r][0]);
                acc[r][1] = fmaf(s, w1v, acc[r][1]);
            }
        }
#pragma unroll
        for (int r = 0; r < 4; r++) {
            int node = nodeBase + rgrp * 4 + r;
            float dv = d0[node];
            BF16S::st(ys1, (size_t)node * 32 + ci0, acc[r][0] * dv);
            BF16S::st(ys1, (size_t)node * 32 + ci0 + 16, acc[r][1] * dv);
        }
        __syncthreads();
    }
}

// ---------------- K2/K3: NPB nodes/block, gather + relu -> O; fused prep_next ----------------
template <int NPB>
__global__ void k_gds(const u16* __restrict__ ys_in, const u32* __restrict__ rpc,
                      const int* __restrict__ col,
                      const float* __restrict__ dinv_p, const void* __restrict__ b,
                      u16* __restrict__ O, const void* __restrict__ wn,
                      const float* __restrict__ dinv_c, u16* __restrict__ ys_out,
                      int cols, const int* __restrict__ flag) {
    int isf32 = *flag;
    __shared__ float sv[NPB * 32];
    __shared__ float swn[1024];
    int t = threadIdx.x;
    int nodeBase = blockIdx.x * NPB;
    int rb = nodeBase / cols;                    // cols % NPB == 0 -> whole block same row
    if (!(rb & 1)) stage(swn, wn, 1024, isf32);  // block-uniform
    int cp = t & 15;
#pragma unroll
    for (int i = 0; i < NPB / 16; i++) {
        int local = (t >> 4) + i * 16;
        int node = nodeBase + local;
        fx2 g = gather2(ys_in, rpc, col, dinv_p, node, cp);
        fx2 v;
        v.x = fmaxf(g.x + rdf(b, 2 * cp, isf32), 0.0f);
        v.y = fmaxf(g.y + rdf(b, 2 * cp + 1, isf32), 0.0f);
        BF16S::st2nt(O, (size_t)node * 16 + cp, v);
        sv[local * 32 + 2 * cp] = v.x;
        sv[local * 32 + 2 * cp + 1] = v.y;
    }
    __syncthreads();
    if (!(rb & 1)) {
#pragma unroll
        for (int i = 0; i < NPB / 16; i++) {
            int item = t + i * 256;
            int childIdx = item >> 5;        // 0..NPB/2-1
            int ci = item & 31;
            int lc = childIdx * 2;           // even local node
            int cc = (nodeBase - rb * cols) + lc;
            int dn = (rb >> 1) * (cols >> 1) + (cc >> 1);
            float a = 0.0f;
#pragma unroll
            for (int k = 0; k < 32; k++) a = fmaf(sv[lc * 32 + k], swn[k * 32 + ci], a);
            BF16S::st(ys_out, (size_t)dn * 32 + ci, a * dinv_c[dn]);
        }
    }
}

// ---------------- K4/K5: NPB parents/block, gather + up-residual + tiled prep_next ----------------
template <int NPB>
__global__ void k_gup(const u16* __restrict__ ys_in, const u32* __restrict__ rpc,
                      const int* __restrict__ col,
                      const float* __restrict__ dinv_p, const void* __restrict__ b,
                      const u16* __restrict__ R, const void* __restrict__ wn,
                      const float* __restrict__ dinv_c, u16* __restrict__ ys_out,
                      int cols_p, const int* __restrict__ flag) {
    constexpr int RPT = NPB / 4;            // child rows per thread
    int isf32 = *flag;
    __shared__ float sv[NPB * 32];
    __shared__ float sch[NPB * 4 * 33];     // padded child rows
    __shared__ float swn[1024];
    int t = threadIdx.x;
    int nodeBase = blockIdx.x * NPB;
    stage(swn, wn, 1024, isf32);
    if (t < NPB * 16) {
        int local = t >> 4, cp = t & 15;
        int node = nodeBase + local;
        fx2 g = gather2(ys_in, rpc, col, dinv_p, node, cp);
        sv[local * 32 + 2 * cp] = fmaxf(g.x + rdf(b, 2 * cp, isf32), 0.0f);
        sv[local * 32 + 2 * cp + 1] = fmaxf(g.y + rdf(b, 2 * cp + 1, isf32), 0.0f);
    }
    __syncthreads();
    int rb = nodeBase / cols_p;
    int ccb = nodeBase - rb * cols_p;
    int cols_c = cols_p * 2;
#pragma unroll
    for (int i = 0; i < NPB / 2; i++) {
        int item = t + i * 256;
        int row = item >> 5, k = item & 31;
        int lp = row >> 2, j = row & 3;
        int ch = (2 * rb + (j >> 1)) * cols_c + 2 * (ccb + lp) + (j & 1);
        sch[row * 33 + k] = bf2f(R[(size_t)ch * 32 + k]) + sv[lp * 32 + k];
    }
    __syncthreads();
    int ci0 = t & 15;
    int rgrp = t >> 4;   // 0..15
    float acc[RPT][2];
#pragma unroll
    for (int r = 0; r < RPT; r++) { acc[r][0] = 0.0f; acc[r][1] = 0.0f; }
#pragma unroll
    for (int k = 0; k < 32; k++) {
        float w0 = swn[k * 32 + ci0];
        float w1v = swn[k * 32 + ci0 + 16];
#pragma unroll
        for (int r = 0; r < RPT; r++) {
            float s = sch[(rgrp * RPT + r) * 33 + k];
            acc[r][0] = fmaf(s, w0, acc[r][0]);
            acc[r][1] = fmaf(s, w1v, acc[r][1]);
        }
    }
#pragma unroll
    for (int r = 0; r < RPT; r++) {
        int row = rgrp * RPT + r;
        int lp = row >> 2, j = row & 3;
        int ch = (2 * rb + (j >> 1)) * cols_c + 2 * (ccb + lp) + (j & 1);
        float dc = dinv_c[ch];
        BF16S::st(ys_out, (size_t)ch * 32 + ci0, acc[r][0] * dc);
        BF16S::st(ys_out, (size_t)ch * 32 + ci0 + 16, acc[r][1] * dc);
    }
}

// ---------------- K6: 32 nodes/block, gather + relu + fc2 -> out ----------------
__global__ void k_gfc2(const u16* __restrict__ ys, const u32* __restrict__ rpc,
                       const int* __restrict__ col,
                       const float* __restrict__ dinv, const void* __restrict__ b5,
                       const void* __restrict__ fw, const void* __restrict__ fb,
                       void* __restrict__ out, int n, const int* __restrict__ flag) {
    int isf32 = *flag;
    __shared__ float sv[1024];
    __shared__ float sw[96];
    __shared__ float sfb[3];
    int t = threadIdx.x;
    if (t < 96) sw[t] = rdf(fw, t, isf32);
    if (t < 3) sfb[t] = rdf(fb, t, isf32);
    int nodeBase = blockIdx.x * 32;
    int cp = t & 15;
#pragma unroll
    for (int i = 0; i < 2; i++) {
        int local = (t >> 4) + i * 16;
        int node = nodeBase + local;
        fx2 g = gather2(ys, rpc, col, dinv, node, cp);
        sv[local * 32 + 2 * cp] = fmaxf(g.x + rdf(b5, 2 * cp, isf32), 0.0f);
        sv[local * 32 + 2 * cp + 1] = fmaxf(g.y + rdf(b5, 2 * cp + 1, isf32), 0.0f);
    }
    __syncthreads();
    if (t < 96) {
        int ln = t / 3, j = t - ln * 3;
        int gn = nodeBase + ln;
        float o = sfb[j];
#pragma unroll
        for (int k = 0; k < 32; k++) o = fmaf(sv[ln * 32 + k], sw[k * 3 + j], o);
        if (isf32) ((float*)out)[(size_t)gn * 3 + j] = o;
        else ((u16*)out)[(size_t)gn * 3 + j] = f2bf(o);
    }
}

extern "C" void kernel_launch(void* const* d_in, const int* in_sizes, int n_in,
                              void* d_out, int out_size, void* d_ws, size_t ws_size,
                              hipStream_t stream) {
    const void* x    = d_in[0];
    const void* fc1w = d_in[1];
    const void* fc1b = d_in[2];
    const void* w1 = d_in[3];  const void* b1 = d_in[4];
    const void* w2 = d_in[5];  const void* b2 = d_in[6];
    const void* w3 = d_in[7];  const void* b3 = d_in[8];
    const void* w4 = d_in[9];  const void* b4 = d_in[10];
    const void* w5 = d_in[11]; const void* b5 = d_in[12];
    const void* fc2w = d_in[13]; const void* fc2b = d_in[14];
    const int* ei0 = (const int*)d_in[18];
    const int* ei1 = (const int*)d_in[19];
    const int* ei2 = (const int*)d_in[20];

    u16* YS0 = (u16*)d_ws;                                  // (N0+1)*32
    u16* A   = YS0 + (size_t)(N0c + 1) * 32;                // N0*32  (h_b residual)
    u16* YS1 = A + (size_t)N0c * 32;                        // (N1+1)*32
    u16* H1  = YS1 + (size_t)(N1c + 1) * 32;                // N1*32  (h1_b residual)
    u16* YS2 = H1 + (size_t)N1c * 32;                       // (N2+1)*32
    float* DINV = (float*)(YS2 + (size_t)(N2c + 1) * 32);   // NT
    u32* RPC  = (u32*)(DINV + NTc);                         // NT
    int* COLA = (int*)(RPC + NTc);                          // NBt*CCAP
    u32* BE   = (u32*)(COLA + (size_t)NBt * CCAP);          // NBt*ECAP
    int* binCursor = (int*)(BE + (size_t)NBt * ECAP);       // NBt
    int* FLAG      = binCursor + NBt;

    float* D0 = DINV; float* D1 = D0 + N0c; float* D2 = D1 + N1c;
    u32* RPC0 = RPC; u32* RPC1 = RPC0 + N0c; u32* RPC2 = RPC1 + N1c;

    const int Bk = 256;

    k_dinit<<<4, Bk, 0, stream>>>((const u32*)x, FLAG, binCursor,
                                  YS0 + (size_t)N0c * 32, YS1 + (size_t)N1c * 32,
                                  YS2 + (size_t)N2c * 32);
    kC_place<<<NCt, 1024, 0, stream>>>(ei0, ei1, ei2, binCursor, BE);
    kD_all<<<NBt, Bk, 0, stream>>>(BE, binCursor, DINV, RPC, COLA);

    // K1: persistent fc1+relu+prep1 -> YS0
    k_fc1prep<<<1960, Bk, 0, stream>>>(x, fc1w, fc1b, w1, D0, YS0, FLAG);
    // K2: gather1 -> A, fused prep2 -> YS1
    k_gds<32><<<N0c / 32, Bk, 0, stream>>>(YS0, RPC0, COLA, D0, b1, A, w2, D1, YS1, NYg, FLAG);
    // K3: gather2 -> H1, fused prep3 -> YS2
    k_gds<16><<<N1c / 16, Bk, 0, stream>>>(YS1, RPC1, COLA, D1, b2, H1, w3, D2, YS2, NYg / 2, FLAG);
    // K4: gather3 + up-residual(H1) + prep4 -> YS1; 8 parents
    k_gup<8><<<N2c / 8, Bk, 0, stream>>>(YS2, RPC2, COLA, D2, b3, H1, w4, D1, YS1, NYg / 4, FLAG);
    // K5: gather4 + up-residual(A) + prep5 -> YS0; 16 parents
    k_gup<16><<<N1c / 16, Bk, 0, stream>>>(YS1, RPC1, COLA, D1, b4, A, w5, D0, YS0, NYg / 2, FLAG);
    // K6: gather5 + fc2 -> out
    k_gfc2<<<N0c / 32, Bk, 0, stream>>>(YS0, RPC0, COLA, D0, b5, fc2w, fc2b, d_out, N0c, FLAG);
}

// Round 17
// 307.042 us; speedup vs baseline: 1.1276x; 1.0145x over previous
//
#include <hip/hip_runtime.h>
#include <hip/hip_bf16.h>

typedef unsigned short u16;
typedef unsigned int u32;
typedef float fx2 __attribute__((ext_vector_type(2)));

#define NXg 784
#define NYg 480
constexpr int N0c = NXg * NYg;   // 376320
constexpr int N1c = N0c / 4;     // 94080
constexpr int N2c = N0c / 16;    // 23520
constexpr int NTc = N0c + N1c + N2c;
constexpr int E0c = 4 * N0c;
constexpr int E1c = 4 * N1c;
constexpr int E2c = 4 * N2c;
// 512-node bins (kD granularity); level-0 bins are exactly full (735*512 == N0c)
constexpr int NB0 = (N0c + 511) / 512;   // 735
constexpr int NB1 = (N1c + 511) / 512;   // 184
constexpr int NB2 = (N2c + 511) / 512;   // 46
constexpr int NBt = NB0 + NB1 + NB2;     // 965
constexpr int ECAP = 2560;               // BE capacity per bin
constexpr int CCAP = 4096;               // COL capacity per bin
// kC chunking: 8192 edges per 1024-thread block
constexpr int CHUNK = 8192;
constexpr int NC0 = (E0c + CHUNK - 1) / CHUNK;   // 184
constexpr int NC1 = (E1c + CHUNK - 1) / CHUNK;   // 46
constexpr int NC2 = (E2c + CHUNK - 1) / CHUNK;   // 12
constexpr int NCt = NC0 + NC1 + NC2;             // 242

__device__ __forceinline__ float bf2f(u16 v) {
    union { u32 u; float f; } t; t.u = ((u32)v) << 16; return t.f;
}
__device__ __forceinline__ u16 f2bf(float f) {
    union { float f; u32 u; } t; t.f = f;
    u32 u = t.u;
    u32 r = (u + 0x7fffu + ((u >> 16) & 1u)) >> 16;   // RNE
    return (u16)r;
}
__device__ __forceinline__ float rdf(const void* p, int i, int isf32) {
    if (isf32) return ((const float*)p)[i];
    return bf2f(((const u16*)p)[i]);
}
__device__ __forceinline__ void stage(float* dst, const void* src, int n, int isf32) {
    int t = threadIdx.x;
    if (isf32) {
        const float* s = (const float*)src;
        for (int i = t; i < n; i += 256) dst[i] = s[i];
    } else {
        const u16* s = (const u16*)src;
        for (int i = t; i < n; i += 256) dst[i] = bf2f(s[i]);
    }
}

struct BF16S {
    typedef u16 T;
    static __device__ __forceinline__ float ld(const T* p, size_t i) { return bf2f(p[i]); }
    static __device__ __forceinline__ void st(T* p, size_t i, float v) { p[i] = f2bf(v); }
    static __device__ __forceinline__ fx2 ld2(const T* p, size_t i) {
        u32 w = ((const u32*)p)[i];
        fx2 r; r.x = bf2f((u16)(w & 0xffffu)); r.y = bf2f((u16)(w >> 16));
        return r;
    }
    static __device__ __forceinline__ void st2nt(T* p, size_t i, fx2 v) {
        u32 w = (u32)f2bf(v.x) | ((u32)f2bf(v.y) << 16);
        __builtin_nontemporal_store(w, (u32*)p + i);
    }
};

__device__ __forceinline__ void lvl_of_bin(int b, int& lv, int& bl) {
    if (b < NB0) { lv = 0; bl = b; }
    else if (b < NB0 + NB1) { lv = 1; bl = b - NB0; }
    else { lv = 2; bl = b - NB0 - NB1; }
}

// ------------- detect dtype + init cursors + dummy ys rows -------------
__global__ void k_dinit(const u32* __restrict__ xw, int* __restrict__ flag,
                        int* __restrict__ binCursor, u16* __restrict__ y0,
                        u16* __restrict__ y1, u16* __restrict__ y2) {
    __shared__ int cnt;
    int t = threadIdx.x;
    int g = blockIdx.x * 256 + t;
    if (blockIdx.x == 0) {
        if (t == 0) cnt = 0;
        __syncthreads();
        u32 w = xw[t];
        int e = (int)((w >> 7) & 0xFFu);
        int hit = ((e >= 90 && e <= 135) || ((w & 0x7FFFu) == 0u)) ? 1 : 0;
        atomicAdd(&cnt, hit);
        __syncthreads();
        if (t == 0) *flag = (cnt < 192) ? 1 : 0;
    }
    if (g < NBt) binCursor[g] = g * ECAP;
    if (blockIdx.x == 1 && t < 32) { y0[t] = 0; y1[t] = 0; y2[t] = 0; }
}

// ------------- phase C: hist + reserve + place packed (src<<9 | dstLow) -------------
__global__ void kC_place(const int* __restrict__ ei0, const int* __restrict__ ei1,
                         const int* __restrict__ ei2, int* __restrict__ binCursor,
                         u32* __restrict__ BE) {
    __shared__ int lc[NB0];
    __shared__ int lb[NB0];
    int b = blockIdx.x, t = threadIdx.x;
    int lv, cl;
    if (b < NC0) { lv = 0; cl = b; }
    else if (b < NC0 + NC1) { lv = 1; cl = b - NC0; }
    else { lv = 2; cl = b - NC0 - NC1; }
    const int* srcp; const int* dstp; int E, nb, binB;
    if (lv == 0) { srcp = ei0; dstp = ei0 + E0c; E = E0c; nb = NB0; binB = 0; }
    else if (lv == 1) { srcp = ei1; dstp = ei1 + E1c; E = E1c; nb = NB1; binB = NB0; }
    else { srcp = ei2; dstp = ei2 + E2c; E = E2c; nb = NB2; binB = NB0 + NB1; }
    for (int i = t; i < nb; i += 1024) lc[i] = 0;
    __syncthreads();
    int e0 = cl * CHUNK, e1 = min(E, e0 + CHUNK);
    for (int i = e0 + t; i < e1; i += 1024) atomicAdd(&lc[dstp[i] >> 9], 1);
    __syncthreads();
    for (int i = t; i < nb; i += 1024) {
        int c = lc[i];
        lb[i] = c ? atomicAdd(&binCursor[binB + i], c) : 0;
        lc[i] = 0;
    }
    __syncthreads();
    for (int i = e0 + t; i < e1; i += 1024) {
        int d = dstp[i];
        int bn = d >> 9;
        int p = atomicAdd(&lc[bn], 1);
        BE[lb[bn] + p] = ((u32)srcp[i] << 9) | (u32)(d & 511);
    }
}

// ------------- phase D: counts -> DINV + RPC + COL fill/scatter; level-0 bins also fc1+prep1 -------------
__global__ void kD_all(const u32* __restrict__ BE, const int* __restrict__ binCursor,
                       float* __restrict__ DINV, u32* __restrict__ RPC,
                       int* __restrict__ colAll,
                       const void* __restrict__ x, const void* __restrict__ fw,
                       const void* __restrict__ fb, const void* __restrict__ w1,
                       u16* __restrict__ ys0, const int* __restrict__ flag) {
    __shared__ int lc[512];
    __shared__ int lst[512];
    __shared__ int lcur[512];
    __shared__ int red[256];
    __shared__ float sw1[1024];
    __shared__ float sfw[128];
    __shared__ float sfb[32];
    __shared__ float sx[256];
    __shared__ float sh[64 * 33];
    int b = blockIdx.x, t = threadIdx.x;
    int lv, bl; lvl_of_bin(b, lv, bl);
    int cbase, nLev, dummy;
    if (lv == 0) { cbase = 0; nLev = N0c; dummy = N0c; }
    else if (lv == 1) { cbase = N0c; nLev = N1c; dummy = N1c; }
    else { cbase = N0c + N1c; nLev = N2c; dummy = N2c; }
    int isf32 = *flag;
    if (lv == 0) {   // stage fc1/w1 weights early (overlaps hist loads)
        stage(sw1, w1, 1024, isf32);
        stage(sfw, fw, 128, isf32);
        stage(sfb, fb, 32, isf32);
    }
    lc[t] = 0; lc[t + 256] = 0;
    __syncthreads();
    int s0 = b * ECAP, s1 = binCursor[b];
    for (int i = s0 + t; i < s1; i += 256) atomicAdd(&lc[BE[i] & 511u], 1);
    __syncthreads();
    int nodeB = bl << 9;
    int pc[2];
    int ps = 0;
#pragma unroll
    for (int j = 0; j < 2; j++) {
        int li = t * 2 + j;
        int node = nodeB + li;
        int c = (node < nLev) ? lc[li] : 0;
        pc[j] = (c + 3) & ~3;
        ps += pc[j];
    }
    red[t] = ps;
    __syncthreads();
    for (int off = 1; off < 256; off <<= 1) {
        int xsc = (t >= off) ? red[t - off] : 0;
        __syncthreads();
        red[t] += xsc;
        __syncthreads();
    }
    int ex = red[t] - ps;
    int tot = red[255];
    int cb = b * CCAP;
    int off = ex;
#pragma unroll
    for (int j = 0; j < 2; j++) {
        int li = t * 2 + j;
        lst[li] = off;
        lcur[li] = off;
        off += pc[j];
    }
    __syncthreads();
#pragma unroll
    for (int j = 0; j < 2; j++) {
        int li = t * 2 + j;
        int node = nodeB + li;
        if (node < nLev) {
            int c = lc[li];
            DINV[cbase + node] = rsqrtf((float)c + 1.0f);
            int rp = cb + lst[li];
            u32 nch = (u32)((c + 3) >> 2);
            RPC[cbase + node] = ((u32)(rp >> 2) << 10) | nch;
        }
    }
    for (int i = t; i < tot; i += 256) colAll[cb + i] = dummy;
    __syncthreads();
    for (int i = s0 + t; i < s1; i += 256) {
        u32 e = BE[i];
        int p = atomicAdd(&lcur[e & 511u], 1);
        colAll[cb + p] = (int)(e >> 9);
    }
    // ---- level-0 bins: fused fc1 + relu + prep1 for this bin's 512 nodes ----
    if (lv == 0) {
        __syncthreads();
        int c = t & 31;
        int ng = t >> 5;       // 0..7
        int ci0 = t & 15;
        int rgrp = t >> 4;     // 0..15
        for (int sub = 0; sub < 8; sub++) {
            int base64 = nodeB + sub * 64;
            sx[t] = rdf(x, base64 * 4 + t, isf32);
            __syncthreads();
#pragma unroll
            for (int i = 0; i < 8; i++) {
                int ln = ng + i * 8;
                float a = sfb[c];
#pragma unroll
                for (int k = 0; k < 4; k++) a = fmaf(sx[ln * 4 + k], sfw[k * 32 + c], a);
                sh[ln * 33 + c] = fmaxf(a, 0.0f);
            }
            __syncthreads();
            float acc[4][2];
#pragma unroll
            for (int r = 0; r < 4; r++) { acc[r][0] = 0.0f; acc[r][1] = 0.0f; }
#pragma unroll
            for (int k = 0; k < 32; k++) {
                float w0 = sw1[k * 32 + ci0];
                float w1v = sw1[k * 32 + ci0 + 16];
#pragma unroll
                for (int r = 0; r < 4; r++) {
                    float s = sh[(rgrp * 4 + r) * 33 + k];
                    acc[r][0] = fmaf(s, w0, acc[r][0]);
                    acc[r][1] = fmaf(s, w1v, acc[r][1]);
                }
            }
#pragma unroll
            for (int r = 0; r < 4; r++) {
                int li = sub * 64 + rgrp * 4 + r;
                int node = nodeB + li;
                float dv = rsqrtf((float)lc[li] + 1.0f);
                BF16S::st(ys0, (size_t)node * 32 + ci0, acc[r][0] * dv);
                BF16S::st(ys0, (size_t)node * 32 + ci0 + 16, acc[r][1] * dv);
            }
            __syncthreads();
        }
    }
}

// ---------------- 2-wide gather core (RPC: packed rowptr|nch) ----------------
__device__ __forceinline__ fx2 gather2(const u16* __restrict__ ys,
                                       const u32* __restrict__ rpc,
                                       const int* __restrict__ col,
                                       const float* __restrict__ dinv,
                                       int node, int cp) {
    u32 v = rpc[node];
    int s0 = (int)((v >> 10) << 2);
    int nch = (int)(v & 1023u);
    fx2 a = BF16S::ld2(ys, (size_t)node * 16 + cp);
    const int4* c4 = (const int4*)(col + s0);
    for (int i = 0; i < nch; i++) {
        int4 cs = c4[i];
        fx2 a0 = BF16S::ld2(ys, (size_t)cs.x * 16 + cp);
        fx2 a1 = BF16S::ld2(ys, (size_t)cs.y * 16 + cp);
        fx2 a2 = BF16S::ld2(ys, (size_t)cs.z * 16 + cp);
        fx2 a3 = BF16S::ld2(ys, (size_t)cs.w * 16 + cp);
        a += (a0 + a1) + (a2 + a3);
    }
    float di = dinv[node];
    a *= di;
    return a;
}

// ---------------- K2/K3: NPB nodes/block, gather + relu -> O; fused prep_next ----------------
template <int NPB>
__global__ void k_gds(const u16* __restrict__ ys_in, const u32* __restrict__ rpc,
                      const int* __restrict__ col,
                      const float* __restrict__ dinv_p, const void* __restrict__ b,
                      u16* __restrict__ O, const void* __restrict__ wn,
                      const float* __restrict__ dinv_c, u16* __restrict__ ys_out,
                      int cols, const int* __restrict__ flag) {
    int isf32 = *flag;
    __shared__ float sv[NPB * 32];
    __shared__ float swn[1024];
    int t = threadIdx.x;
    int nodeBase = blockIdx.x * NPB;
    int rb = nodeBase / cols;
    if (!(rb & 1)) stage(swn, wn, 1024, isf32);
    int cp = t & 15;
#pragma unroll
    for (int i = 0; i < NPB / 16; i++) {
        int local = (t >> 4) + i * 16;
        int node = nodeBase + local;
        fx2 g = gather2(ys_in, rpc, col, dinv_p, node, cp);
        fx2 v;
        v.x = fmaxf(g.x + rdf(b, 2 * cp, isf32), 0.0f);
        v.y = fmaxf(g.y + rdf(b, 2 * cp + 1, isf32), 0.0f);
        BF16S::st2nt(O, (size_t)node * 16 + cp, v);
        sv[local * 32 + 2 * cp] = v.x;
        sv[local * 32 + 2 * cp + 1] = v.y;
    }
    __syncthreads();
    if (!(rb & 1)) {
#pragma unroll
        for (int i = 0; i < NPB / 16; i++) {
            int item = t + i * 256;
            int childIdx = item >> 5;
            int ci = item & 31;
            int lc = childIdx * 2;
            int cc = (nodeBase - rb * cols) + lc;
            int dn = (rb >> 1) * (cols >> 1) + (cc >> 1);
            float a = 0.0f;
#pragma unroll
            for (int k = 0; k < 32; k++) a = fmaf(sv[lc * 32 + k], swn[k * 32 + ci], a);
            BF16S::st(ys_out, (size_t)dn * 32 + ci, a * dinv_c[dn]);
        }
    }
}

// ---------------- K4/K5: NPB parents/block, gather + up-residual + tiled prep_next ----------------
template <int NPB>
__global__ void k_gup(const u16* __restrict__ ys_in, const u32* __restrict__ rpc,
                      const int* __restrict__ col,
                      const float* __restrict__ dinv_p, const void* __restrict__ b,
                      const u16* __restrict__ R, const void* __restrict__ wn,
                      const float* __restrict__ dinv_c, u16* __restrict__ ys_out,
                      int cols_p, const int* __restrict__ flag) {
    constexpr int RPT = NPB / 4;
    int isf32 = *flag;
    __shared__ float sv[NPB * 32];
    __shared__ float sch[NPB * 4 * 33];
    __shared__ float swn[1024];
    int t = threadIdx.x;
    int nodeBase = blockIdx.x * NPB;
    stage(swn, wn, 1024, isf32);
    if (t < NPB * 16) {
        int local = t >> 4, cp = t & 15;
        int node = nodeBase + local;
        fx2 g = gather2(ys_in, rpc, col, dinv_p, node, cp);
        sv[local * 32 + 2 * cp] = fmaxf(g.x + rdf(b, 2 * cp, isf32), 0.0f);
        sv[local * 32 + 2 * cp + 1] = fmaxf(g.y + rdf(b, 2 * cp + 1, isf32), 0.0f);
    }
    __syncthreads();
    int rb = nodeBase / cols_p;
    int ccb = nodeBase - rb * cols_p;
    int cols_c = cols_p * 2;
#pragma unroll
    for (int i = 0; i < NPB / 2; i++) {
        int item = t + i * 256;
        int row = item >> 5, k = item & 31;
        int lp = row >> 2, j = row & 3;
        int ch = (2 * rb + (j >> 1)) * cols_c + 2 * (ccb + lp) + (j & 1);
        sch[row * 33 + k] = bf2f(R[(size_t)ch * 32 + k]) + sv[lp * 32 + k];
    }
    __syncthreads();
    int ci0 = t & 15;
    int rgrp = t >> 4;
    float acc[RPT][2];
#pragma unroll
    for (int r = 0; r < RPT; r++) { acc[r][0] = 0.0f; acc[r][1] = 0.0f; }
#pragma unroll
    for (int k = 0; k < 32; k++) {
        float w0 = swn[k * 32 + ci0];
        float w1v = swn[k * 32 + ci0 + 16];
#pragma unroll
        for (int r = 0; r < RPT; r++) {
            float s = sch[(rgrp * RPT + r) * 33 + k];
            acc[r][0] = fmaf(s, w0, acc[r][0]);
            acc[r][1] = fmaf(s, w1v, acc[r][1]);
        }
    }
#pragma unroll
    for (int r = 0; r < RPT; r++) {
        int row = rgrp * RPT + r;
        int lp = row >> 2, j = row & 3;
        int ch = (2 * rb + (j >> 1)) * cols_c + 2 * (ccb + lp) + (j & 1);
        float dc = dinv_c[ch];
        BF16S::st(ys_out, (size_t)ch * 32 + ci0, acc[r][0] * dc);
        BF16S::st(ys_out, (size_t)ch * 32 + ci0 + 16, acc[r][1] * dc);
    }
}

// ---------------- K6: 64 nodes/block, gather + relu + fc2 -> out ----------------
__global__ void k_gfc2(const u16* __restrict__ ys, const u32* __restrict__ rpc,
                       const int* __restrict__ col,
                       const float* __restrict__ dinv, const void* __restrict__ b5,
                       const void* __restrict__ fw, const void* __restrict__ fb,
                       void* __restrict__ out, int n, const int* __restrict__ flag) {
    int isf32 = *flag;
    __shared__ float sv[2048];
    __shared__ float sw[96];
    __shared__ float sfb3[3];
    int t = threadIdx.x;
    if (t < 96) sw[t] = rdf(fw, t, isf32);
    if (t < 3) sfb3[t] = rdf(fb, t, isf32);
    int nodeBase = blockIdx.x * 64;
    int cp = t & 15;
#pragma unroll
    for (int i = 0; i < 4; i++) {
        int local = (t >> 4) + i * 16;
        int node = nodeBase + local;
        fx2 g = gather2(ys, rpc, col, dinv, node, cp);
        sv[local * 32 + 2 * cp] = fmaxf(g.x + rdf(b5, 2 * cp, isf32), 0.0f);
        sv[local * 32 + 2 * cp + 1] = fmaxf(g.y + rdf(b5, 2 * cp + 1, isf32), 0.0f);
    }
    __syncthreads();
    if (t < 192) {
        int ln = t / 3, j = t - ln * 3;
        int gn = nodeBase + ln;
        float o = sfb3[j];
#pragma unroll
        for (int k = 0; k < 32; k++) o = fmaf(sv[ln * 32 + k], sw[k * 3 + j], o);
        if (isf32) ((float*)out)[(size_t)gn * 3 + j] = o;
        else ((u16*)out)[(size_t)gn * 3 + j] = f2bf(o);
    }
}

extern "C" void kernel_launch(void* const* d_in, const int* in_sizes, int n_in,
                              void* d_out, int out_size, void* d_ws, size_t ws_size,
                              hipStream_t stream) {
    const void* x    = d_in[0];
    const void* fc1w = d_in[1];
    const void* fc1b = d_in[2];
    const void* w1 = d_in[3];  const void* b1 = d_in[4];
    const void* w2 = d_in[5];  const void* b2 = d_in[6];
    const void* w3 = d_in[7];  const void* b3 = d_in[8];
    const void* w4 = d_in[9];  const void* b4 = d_in[10];
    const void* w5 = d_in[11]; const void* b5 = d_in[12];
    const void* fc2w = d_in[13]; const void* fc2b = d_in[14];
    const int* ei0 = (const int*)d_in[18];
    const int* ei1 = (const int*)d_in[19];
    const int* ei2 = (const int*)d_in[20];

    u16* YS0 = (u16*)d_ws;                                  // (N0+1)*32
    u16* A   = YS0 + (size_t)(N0c + 1) * 32;                // N0*32  (h_b residual)
    u16* YS1 = A + (size_t)N0c * 32;                        // (N1+1)*32
    u16* H1  = YS1 + (size_t)(N1c + 1) * 32;                // N1*32  (h1_b residual)
    u16* YS2 = H1 + (size_t)N1c * 32;                       // (N2+1)*32
    float* DINV = (float*)(YS2 + (size_t)(N2c + 1) * 32);   // NT
    u32* RPC  = (u32*)(DINV + NTc);                         // NT
    int* COLA = (int*)(RPC + NTc);                          // NBt*CCAP
    u32* BE   = (u32*)(COLA + (size_t)NBt * CCAP);          // NBt*ECAP
    int* binCursor = (int*)(BE + (size_t)NBt * ECAP);       // NBt
    int* FLAG      = binCursor + NBt;

    float* D0 = DINV; float* D1 = D0 + N0c; float* D2 = D1 + N1c;
    u32* RPC0 = RPC; u32* RPC1 = RPC0 + N0c; u32* RPC2 = RPC1 + N1c;

    const int Bk = 256;

    k_dinit<<<4, Bk, 0, stream>>>((const u32*)x, FLAG, binCursor,
                                  YS0 + (size_t)N0c * 32, YS1 + (size_t)N1c * 32,
                                  YS2 + (size_t)N2c * 32);
    kC_place<<<NCt, 1024, 0, stream>>>(ei0, ei1, ei2, binCursor, BE);
    // kD: CSR finalize for all bins + fused fc1+relu+prep1 (level-0 bins) -> YS0
    kD_all<<<NBt, Bk, 0, stream>>>(BE, binCursor, DINV, RPC, COLA,
                                   x, fc1w, fc1b, w1, YS0, FLAG);

    // K2: gather1 -> A, fused prep2 -> YS1
    k_gds<32><<<N0c / 32, Bk, 0, stream>>>(YS0, RPC0, COLA, D0, b1, A, w2, D1, YS1, NYg, FLAG);
    // K3: gather2 -> H1, fused prep3 -> YS2
    k_gds<16><<<N1c / 16, Bk, 0, stream>>>(YS1, RPC1, COLA, D1, b2, H1, w3, D2, YS2, NYg / 2, FLAG);
    // K4: gather3 + up-residual(H1) + prep4 -> YS1; 8 parents
    k_gup<8><<<N2c / 8, Bk, 0, stream>>>(YS2, RPC2, COLA, D2, b3, H1, w4, D1, YS1, NYg / 4, FLAG);
    // K5: gather4 + up-residual(A) + prep5 -> YS0; 16 parents
    k_gup<16><<<N1c / 16, Bk, 0, stream>>>(YS1, RPC1, COLA, D1, b4, A, w5, D0, YS0, NYg / 2, FLAG);
    // K6: gather5 + fc2 -> out (64 nodes/block)
    k_gfc2<<<N0c / 64, Bk, 0, stream>>>(YS0, RPC0, COLA, D0, b5, fc2w, fc2b, d_out, N0c, FLAG);
}

// Round 18
// 302.854 us; speedup vs baseline: 1.1432x; 1.0138x over previous
//
#include <hip/hip_runtime.h>
#include <hip/hip_bf16.h>

typedef unsigned short u16;
typedef unsigned int u32;
typedef float fx2 __attribute__((ext_vector_type(2)));
typedef float fx4 __attribute__((ext_vector_type(4)));

#define NXg 784
#define NYg 480
constexpr int N0c = NXg * NYg;   // 376320
constexpr int N1c = N0c / 4;     // 94080
constexpr int N2c = N0c / 16;    // 23520
constexpr int NTc = N0c + N1c + N2c;
constexpr int E0c = 4 * N0c;
constexpr int E1c = 4 * N1c;
constexpr int E2c = 4 * N2c;
// 512-node bins (kD granularity); level-0 bins exactly full (735*512 == N0c)
constexpr int NB0 = (N0c + 511) / 512;   // 735
constexpr int NB1 = (N1c + 511) / 512;   // 184
constexpr int NB2 = (N2c + 511) / 512;   // 46
constexpr int NBt = NB0 + NB1 + NB2;     // 965
constexpr int ECAP = 2560;
constexpr int CCAP = 4096;
// kC chunking: 8192 edges per 1024-thread block
constexpr int CHUNK = 8192;
constexpr int NC0 = (E0c + CHUNK - 1) / CHUNK;   // 184
constexpr int NC1 = (E1c + CHUNK - 1) / CHUNK;   // 46
constexpr int NC2 = (E2c + CHUNK - 1) / CHUNK;   // 12
constexpr int NCt = NC0 + NC1 + NC2;             // 242

__device__ __forceinline__ float bf2f(u16 v) {
    union { u32 u; float f; } t; t.u = ((u32)v) << 16; return t.f;
}
__device__ __forceinline__ u16 f2bf(float f) {
    union { float f; u32 u; } t; t.f = f;
    u32 u = t.u;
    u32 r = (u + 0x7fffu + ((u >> 16) & 1u)) >> 16;   // RNE
    return (u16)r;
}
__device__ __forceinline__ float rdf(const void* p, int i, int isf32) {
    if (isf32) return ((const float*)p)[i];
    return bf2f(((const u16*)p)[i]);
}
__device__ __forceinline__ void stage(float* dst, const void* src, int n, int isf32) {
    int t = threadIdx.x;
    if (isf32) {
        const float* s = (const float*)src;
        for (int i = t; i < n; i += 256) dst[i] = s[i];
    } else {
        const u16* s = (const u16*)src;
        for (int i = t; i < n; i += 256) dst[i] = bf2f(s[i]);
    }
}

struct BF16S {
    typedef u16 T;
    static __device__ __forceinline__ float ld(const T* p, size_t i) { return bf2f(p[i]); }
    static __device__ __forceinline__ void st(T* p, size_t i, float v) { p[i] = f2bf(v); }
    static __device__ __forceinline__ fx2 ld2(const T* p, size_t i) {
        u32 w = ((const u32*)p)[i];
        fx2 r; r.x = bf2f((u16)(w & 0xffffu)); r.y = bf2f((u16)(w >> 16));
        return r;
    }
    static __device__ __forceinline__ void st2nt(T* p, size_t i, fx2 v) {
        u32 w = (u32)f2bf(v.x) | ((u32)f2bf(v.y) << 16);
        __builtin_nontemporal_store(w, (u32*)p + i);
    }
};

__device__ __forceinline__ void lvl_of_bin(int b, int& lv, int& bl) {
    if (b < NB0) { lv = 0; bl = b; }
    else if (b < NB0 + NB1) { lv = 1; bl = b - NB0; }
    else { lv = 2; bl = b - NB0 - NB1; }
}

// ------------- detect dtype + init cursors + dummy ys rows -------------
__global__ void k_dinit(const u32* __restrict__ xw, int* __restrict__ flag,
                        int* __restrict__ binCursor, u16* __restrict__ y0,
                        u16* __restrict__ y1, u16* __restrict__ y2) {
    __shared__ int cnt;
    int t = threadIdx.x;
    int g = blockIdx.x * 256 + t;
    if (blockIdx.x == 0) {
        if (t == 0) cnt = 0;
        __syncthreads();
        u32 w = xw[t];
        int e = (int)((w >> 7) & 0xFFu);
        int hit = ((e >= 90 && e <= 135) || ((w & 0x7FFFu) == 0u)) ? 1 : 0;
        atomicAdd(&cnt, hit);
        __syncthreads();
        if (t == 0) *flag = (cnt < 192) ? 1 : 0;
    }
    if (g < NBt) binCursor[g] = g * ECAP;
    if (blockIdx.x == 1 && t < 32) { y0[t] = 0; y1[t] = 0; y2[t] = 0; }
}

// ------------- phase C: hist + reserve + place packed (src<<9 | dstLow) -------------
__global__ void kC_place(const int* __restrict__ ei0, const int* __restrict__ ei1,
                         const int* __restrict__ ei2, int* __restrict__ binCursor,
                         u32* __restrict__ BE) {
    __shared__ int lc[NB0];
    __shared__ int lb[NB0];
    int b = blockIdx.x, t = threadIdx.x;
    int lv, cl;
    if (b < NC0) { lv = 0; cl = b; }
    else if (b < NC0 + NC1) { lv = 1; cl = b - NC0; }
    else { lv = 2; cl = b - NC0 - NC1; }
    const int* srcp; const int* dstp; int E, nb, binB;
    if (lv == 0) { srcp = ei0; dstp = ei0 + E0c; E = E0c; nb = NB0; binB = 0; }
    else if (lv == 1) { srcp = ei1; dstp = ei1 + E1c; E = E1c; nb = NB1; binB = NB0; }
    else { srcp = ei2; dstp = ei2 + E2c; E = E2c; nb = NB2; binB = NB0 + NB1; }
    for (int i = t; i < nb; i += 1024) lc[i] = 0;
    __syncthreads();
    int e0 = cl * CHUNK, e1 = min(E, e0 + CHUNK);
    for (int i = e0 + t; i < e1; i += 1024) atomicAdd(&lc[dstp[i] >> 9], 1);
    __syncthreads();
    for (int i = t; i < nb; i += 1024) {
        int c = lc[i];
        lb[i] = c ? atomicAdd(&binCursor[binB + i], c) : 0;
        lc[i] = 0;
    }
    __syncthreads();
    for (int i = e0 + t; i < e1; i += 1024) {
        int d = dstp[i];
        int bn = d >> 9;
        int p = atomicAdd(&lc[bn], 1);
        BE[lb[bn] + p] = ((u32)srcp[i] << 9) | (u32)(d & 511);
    }
}

// ------------- phase D: CSR finalize; level-0 bins also fused fc1+relu+prep1 -------------
__global__ void kD_all(const u32* __restrict__ BE, const int* __restrict__ binCursor,
                       float* __restrict__ DINV, u32* __restrict__ RPC,
                       int* __restrict__ colAll,
                       const void* __restrict__ x, const void* __restrict__ fw,
                       const void* __restrict__ fb, const void* __restrict__ w1,
                       u16* __restrict__ ys0, const int* __restrict__ flag) {
    __shared__ int lc[512];                     // persistent (degrees)
    __shared__ float sw1p[1024];                // persistent: W1 pair-interleaved
    __shared__ float sfw[128];
    __shared__ float sfb[32];
    __shared__ __align__(16) float uni[2432];   // overlay: {lst,lcur,red} then {sx,shT}
    int* lst = (int*)uni;            // 512
    int* lcur = lst + 512;           // 512
    int* red = lcur + 512;           // 256
    float* sx = uni;                 // 256  (fc1 phase)
    float* shT = uni + 256;          // 32*68 = 2176 (fc1 phase, transposed + pad 68)
    int b = blockIdx.x, t = threadIdx.x;
    int lv, bl; lvl_of_bin(b, lv, bl);
    int cbase, nLev, dummy;
    if (lv == 0) { cbase = 0; nLev = N0c; dummy = N0c; }
    else if (lv == 1) { cbase = N0c; nLev = N1c; dummy = N1c; }
    else { cbase = N0c + N1c; nLev = N2c; dummy = N2c; }
    int isf32 = *flag;
    if (lv == 0) {
        // W1 pair-interleave: sw1p[k*32 + 2c + h] = W1[k*32 + c + 16h], c in [0,16)
        for (int i = t; i < 1024; i += 256) {
            int k = i >> 5, j = i & 31;
            sw1p[i] = rdf(w1, k * 32 + (j >> 1) + 16 * (j & 1), isf32);
        }
        stage(sfw, fw, 128, isf32);
        stage(sfb, fb, 32, isf32);
    }
    lc[t] = 0; lc[t + 256] = 0;
    __syncthreads();
    int s0 = b * ECAP, s1 = binCursor[b];
    for (int i = s0 + t; i < s1; i += 256) atomicAdd(&lc[BE[i] & 511u], 1);
    __syncthreads();
    int nodeB = bl << 9;
    int pc[2];
    int ps = 0;
#pragma unroll
    for (int j = 0; j < 2; j++) {
        int li = t * 2 + j;
        int node = nodeB + li;
        int c = (node < nLev) ? lc[li] : 0;
        pc[j] = (c + 3) & ~3;
        ps += pc[j];
    }
    red[t] = ps;
    __syncthreads();
    for (int off = 1; off < 256; off <<= 1) {
        int xsc = (t >= off) ? red[t - off] : 0;
        __syncthreads();
        red[t] += xsc;
        __syncthreads();
    }
    int ex = red[t] - ps;
    int tot = red[255];
    int cb = b * CCAP;
    int off = ex;
#pragma unroll
    for (int j = 0; j < 2; j++) {
        int li = t * 2 + j;
        lst[li] = off;
        lcur[li] = off;
        off += pc[j];
    }
    __syncthreads();
#pragma unroll
    for (int j = 0; j < 2; j++) {
        int li = t * 2 + j;
        int node = nodeB + li;
        if (node < nLev) {
            int c = lc[li];
            DINV[cbase + node] = rsqrtf((float)c + 1.0f);
            int rp = cb + lst[li];
            u32 nch = (u32)((c + 3) >> 2);
            RPC[cbase + node] = ((u32)(rp >> 2) << 10) | nch;
        }
    }
    for (int i = t; i < tot; i += 256) colAll[cb + i] = dummy;
    __syncthreads();
    for (int i = s0 + t; i < s1; i += 256) {
        u32 e = BE[i];
        int p = atomicAdd(&lcur[e & 511u], 1);
        colAll[cb + p] = (int)(e >> 9);
    }
    // ---- level-0 bins: fused fc1 + relu + prep1 (lst/lcur/red now dead; overlay as sx/shT) ----
    if (lv == 0) {
        __syncthreads();
        int c = t & 31;
        int ng = t >> 5;       // 0..7
        int ci0 = t & 15;
        int rgrp = t >> 4;     // 0..15
        for (int sub = 0; sub < 8; sub++) {
            int base64 = nodeB + sub * 64;
            sx[t] = rdf(x, base64 * 4 + t, isf32);
            __syncthreads();
#pragma unroll
            for (int i = 0; i < 8; i++) {
                int ln = ng + i * 8;
                float a = sfb[c];
#pragma unroll
                for (int k = 0; k < 4; k++) a = fmaf(sx[ln * 4 + k], sfw[k * 32 + c], a);
                shT[c * 68 + ln] = fmaxf(a, 0.0f);   // transposed: [k][node], pad 68
            }
            __syncthreads();
            float acc[4][2];
#pragma unroll
            for (int r = 0; r < 4; r++) { acc[r][0] = 0.0f; acc[r][1] = 0.0f; }
#pragma unroll
            for (int k = 0; k < 32; k++) {
                fx2 wp = *(const fx2*)&sw1p[k * 32 + 2 * ci0];      // b64
                fx4 rv = *(const fx4*)&shT[k * 68 + rgrp * 4];       // b128 (broadcast x16)
#pragma unroll
                for (int r = 0; r < 4; r++) {
                    acc[r][0] = fmaf(rv[r], wp.x, acc[r][0]);
                    acc[r][1] = fmaf(rv[r], wp.y, acc[r][1]);
                }
            }
#pragma unroll
            for (int r = 0; r < 4; r++) {
                int li = sub * 64 + rgrp * 4 + r;
                int node = nodeB + li;
                float dv = rsqrtf((float)lc[li] + 1.0f);
                BF16S::st(ys0, (size_t)node * 32 + ci0, acc[r][0] * dv);
                BF16S::st(ys0, (size_t)node * 32 + ci0 + 16, acc[r][1] * dv);
            }
            __syncthreads();
        }
    }
}

// ---------------- 2-wide gather core (RPC: packed rowptr|nch) ----------------
__device__ __forceinline__ fx2 gather2(const u16* __restrict__ ys,
                                       const u32* __restrict__ rpc,
                                       const int* __restrict__ col,
                                       const float* __restrict__ dinv,
                                       int node, int cp) {
    u32 v = rpc[node];
    int s0 = (int)((v >> 10) << 2);
    int nch = (int)(v & 1023u);
    fx2 a = BF16S::ld2(ys, (size_t)node * 16 + cp);
    const int4* c4 = (const int4*)(col + s0);
    for (int i = 0; i < nch; i++) {
        int4 cs = c4[i];
        fx2 a0 = BF16S::ld2(ys, (size_t)cs.x * 16 + cp);
        fx2 a1 = BF16S::ld2(ys, (size_t)cs.y * 16 + cp);
        fx2 a2 = BF16S::ld2(ys, (size_t)cs.z * 16 + cp);
        fx2 a3 = BF16S::ld2(ys, (size_t)cs.w * 16 + cp);
        a += (a0 + a1) + (a2 + a3);
    }
    float di = dinv[node];
    a *= di;
    return a;
}

// ---------------- K2/K3: NPB nodes/block, gather + relu -> O; fused prep_next ----------------
template <int NPB>
__global__ void k_gds(const u16* __restrict__ ys_in, const u32* __restrict__ rpc,
                      const int* __restrict__ col,
                      const float* __restrict__ dinv_p, const void* __restrict__ b,
                      u16* __restrict__ O, const void* __restrict__ wn,
                      const float* __restrict__ dinv_c, u16* __restrict__ ys_out,
                      int cols, const int* __restrict__ flag) {
    int isf32 = *flag;
    __shared__ float sv[NPB * 32];
    __shared__ float swn[1024];
    int t = threadIdx.x;
    int nodeBase = blockIdx.x * NPB;
    int rb = nodeBase / cols;
    if (!(rb & 1)) stage(swn, wn, 1024, isf32);
    int cp = t & 15;
#pragma unroll
    for (int i = 0; i < NPB / 16; i++) {
        int local = (t >> 4) + i * 16;
        int node = nodeBase + local;
        fx2 g = gather2(ys_in, rpc, col, dinv_p, node, cp);
        fx2 v;
        v.x = fmaxf(g.x + rdf(b, 2 * cp, isf32), 0.0f);
        v.y = fmaxf(g.y + rdf(b, 2 * cp + 1, isf32), 0.0f);
        BF16S::st2nt(O, (size_t)node * 16 + cp, v);
        sv[local * 32 + 2 * cp] = v.x;
        sv[local * 32 + 2 * cp + 1] = v.y;
    }
    __syncthreads();
    if (!(rb & 1)) {
#pragma unroll
        for (int i = 0; i < NPB / 16; i++) {
            int item = t + i * 256;
            int childIdx = item >> 5;
            int ci = item & 31;
            int lc = childIdx * 2;
            int cc = (nodeBase - rb * cols) + lc;
            int dn = (rb >> 1) * (cols >> 1) + (cc >> 1);
            float a = 0.0f;
#pragma unroll
            for (int k = 0; k < 32; k++) a = fmaf(sv[lc * 32 + k], swn[k * 32 + ci], a);
            BF16S::st(ys_out, (size_t)dn * 32 + ci, a * dinv_c[dn]);
        }
    }
}

// ---------------- K4/K5: NPB parents/block, gather + up-residual + tiled prep_next ----------------
template <int NPB>
__global__ void k_gup(const u16* __restrict__ ys_in, const u32* __restrict__ rpc,
                      const int* __restrict__ col,
                      const float* __restrict__ dinv_p, const void* __restrict__ b,
                      const u16* __restrict__ R, const void* __restrict__ wn,
                      const float* __restrict__ dinv_c, u16* __restrict__ ys_out,
                      int cols_p, const int* __restrict__ flag) {
    constexpr int RPT = NPB / 4;
    int isf32 = *flag;
    __shared__ float sv[NPB * 32];
    __shared__ float sch[NPB * 4 * 33];
    __shared__ float swn[1024];
    int t = threadIdx.x;
    int nodeBase = blockIdx.x * NPB;
    stage(swn, wn, 1024, isf32);
    if (t < NPB * 16) {
        int local = t >> 4, cp = t & 15;
        int node = nodeBase + local;
        fx2 g = gather2(ys_in, rpc, col, dinv_p, node, cp);
        sv[local * 32 + 2 * cp] = fmaxf(g.x + rdf(b, 2 * cp, isf32), 0.0f);
        sv[local * 32 + 2 * cp + 1] = fmaxf(g.y + rdf(b, 2 * cp + 1, isf32), 0.0f);
    }
    __syncthreads();
    int rb = nodeBase / cols_p;
    int ccb = nodeBase - rb * cols_p;
    int cols_c = cols_p * 2;
#pragma unroll
    for (int i = 0; i < NPB / 2; i++) {
        int item = t + i * 256;
        int row = item >> 5, k = item & 31;
        int lp = row >> 2, j = row & 3;
        int ch = (2 * rb + (j >> 1)) * cols_c + 2 * (ccb + lp) + (j & 1);
        sch[row * 33 + k] = bf2f(R[(size_t)ch * 32 + k]) + sv[lp * 32 + k];
    }
    __syncthreads();
    int ci0 = t & 15;
    int rgrp = t >> 4;
    float acc[RPT][2];
#pragma unroll
    for (int r = 0; r < RPT; r++) { acc[r][0] = 0.0f; acc[r][1] = 0.0f; }
#pragma unroll
    for (int k = 0; k < 32; k++) {
        float w0 = swn[k * 32 + ci0];
        float w1v = swn[k * 32 + ci0 + 16];
#pragma unroll
        for (int r = 0; r < RPT; r++) {
            float s = sch[(rgrp * RPT + r) * 33 + k];
            acc[r][0] = fmaf(s, w0, acc[r][0]);
            acc[r][1] = fmaf(s, w1v, acc[r][1]);
        }
    }
#pragma unroll
    for (int r = 0; r < RPT; r++) {
        int row = rgrp * RPT + r;
        int lp = row >> 2, j = row & 3;
        int ch = (2 * rb + (j >> 1)) * cols_c + 2 * (ccb + lp) + (j & 1);
        float dc = dinv_c[ch];
        BF16S::st(ys_out, (size_t)ch * 32 + ci0, acc[r][0] * dc);
        BF16S::st(ys_out, (size_t)ch * 32 + ci0 + 16, acc[r][1] * dc);
    }
}

// ---------------- K6: 64 nodes/block, gather + relu + fc2 -> out ----------------
__global__ void k_gfc2(const u16* __restrict__ ys, const u32* __restrict__ rpc,
                       const int* __restrict__ col,
                       const float* __restrict__ dinv, const void* __restrict__ b5,
                       const void* __restrict__ fw, const void* __restrict__ fb,
                       void* __restrict__ out, int n, const int* __restrict__ flag) {
    int isf32 = *flag;
    __shared__ float sv[2048];
    __shared__ float sw[96];
    __shared__ float sfb3[3];
    int t = threadIdx.x;
    if (t < 96) sw[t] = rdf(fw, t, isf32);
    if (t < 3) sfb3[t] = rdf(fb, t, isf32);
    int nodeBase = blockIdx.x * 64;
    int cp = t & 15;
#pragma unroll
    for (int i = 0; i < 4; i++) {
        int local = (t >> 4) + i * 16;
        int node = nodeBase + local;
        fx2 g = gather2(ys, rpc, col, dinv, node, cp);
        sv[local * 32 + 2 * cp] = fmaxf(g.x + rdf(b5, 2 * cp, isf32), 0.0f);
        sv[local * 32 + 2 * cp + 1] = fmaxf(g.y + rdf(b5, 2 * cp + 1, isf32), 0.0f);
    }
    __syncthreads();
    if (t < 192) {
        int ln = t / 3, j = t - ln * 3;
        int gn = nodeBase + ln;
        float o = sfb3[j];
#pragma unroll
        for (int k = 0; k < 32; k++) o = fmaf(sv[ln * 32 + k], sw[k * 3 + j], o);
        if (isf32) ((float*)out)[(size_t)gn * 3 + j] = o;
        else ((u16*)out)[(size_t)gn * 3 + j] = f2bf(o);
    }
}

extern "C" void kernel_launch(void* const* d_in, const int* in_sizes, int n_in,
                              void* d_out, int out_size, void* d_ws, size_t ws_size,
                              hipStream_t stream) {
    const void* x    = d_in[0];
    const void* fc1w = d_in[1];
    const void* fc1b = d_in[2];
    const void* w1 = d_in[3];  const void* b1 = d_in[4];
    const void* w2 = d_in[5];  const void* b2 = d_in[6];
    const void* w3 = d_in[7];  const void* b3 = d_in[8];
    const void* w4 = d_in[9];  const void* b4 = d_in[10];
    const void* w5 = d_in[11]; const void* b5 = d_in[12];
    const void* fc2w = d_in[13]; const void* fc2b = d_in[14];
    const int* ei0 = (const int*)d_in[18];
    const int* ei1 = (const int*)d_in[19];
    const int* ei2 = (const int*)d_in[20];

    u16* YS0 = (u16*)d_ws;
    u16* A   = YS0 + (size_t)(N0c + 1) * 32;
    u16* YS1 = A + (size_t)N0c * 32;
    u16* H1  = YS1 + (size_t)(N1c + 1) * 32;
    u16* YS2 = H1 + (size_t)N1c * 32;
    float* DINV = (float*)(YS2 + (size_t)(N2c + 1) * 32);
    u32* RPC  = (u32*)(DINV + NTc);
    int* COLA = (int*)(RPC + NTc);
    u32* BE   = (u32*)(COLA + (size_t)NBt * CCAP);
    int* binCursor = (int*)(BE + (size_t)NBt * ECAP);
    int* FLAG      = binCursor + NBt;

    float* D0 = DINV; float* D1 = D0 + N0c; float* D2 = D1 + N1c;
    u32* RPC0 = RPC; u32* RPC1 = RPC0 + N0c; u32* RPC2 = RPC1 + N1c;

    const int Bk = 256;

    k_dinit<<<4, Bk, 0, stream>>>((const u32*)x, FLAG, binCursor,
                                  YS0 + (size_t)N0c * 32, YS1 + (size_t)N1c * 32,
                                  YS2 + (size_t)N2c * 32);
    kC_place<<<NCt, 1024, 0, stream>>>(ei0, ei1, ei2, binCursor, BE);
    kD_all<<<NBt, Bk, 0, stream>>>(BE, binCursor, DINV, RPC, COLA,
                                   x, fc1w, fc1b, w1, YS0, FLAG);

    // K2: gather1 -> A, fused prep2 -> YS1
    k_gds<32><<<N0c / 32, Bk, 0, stream>>>(YS0, RPC0, COLA, D0, b1, A, w2, D1, YS1, NYg, FLAG);
    // K3: gather2 -> H1, fused prep3 -> YS2
    k_gds<16><<<N1c / 16, Bk, 0, stream>>>(YS1, RPC1, COLA, D1, b2, H1, w3, D2, YS2, NYg / 2, FLAG);
    // K4: gather3 + up-residual(H1) + prep4 -> YS1; 8 parents
    k_gup<8><<<N2c / 8, Bk, 0, stream>>>(YS2, RPC2, COLA, D2, b3, H1, w4, D1, YS1, NYg / 4, FLAG);
    // K5: gather4 + up-residual(A) + prep5 -> YS0; 16 parents
    k_gup<16><<<N1c / 16, Bk, 0, stream>>>(YS1, RPC1, COLA, D1, b4, A, w5, D0, YS0, NYg / 2, FLAG);
    // K6: gather5 + fc2 -> out (64 nodes/block)
    k_gfc2<<<N0c / 64, Bk, 0, stream>>>(YS0, RPC0, COLA, D0, b5, fc2w, fc2b, d_out, N0c, FLAG);
}